// Round 5
// baseline (454.323 us; speedup 1.0000x reference)
//
#include <hip/hip_runtime.h>

#define D_MODEL 4096
#define NEXP    64
#define NTOK    16384
#define NKS     128              // k-steps of 32: 4096/32
#define NCH     64               // chunks of 64 k (2 k-steps)

typedef _Float16 half8 __attribute__((ext_vector_type(8)));
typedef float    f32x4 __attribute__((ext_vector_type(4)));

// Dekker-style split of 8 fp32 into f16 hi + f16 lo planes (RTZ; lo catches residual)
__device__ __forceinline__ void split8(float4 a, float4 b, half8& hi, half8& lo) {
    auto h0 = __builtin_amdgcn_cvt_pkrtz(a.x, a.y);
    auto h1 = __builtin_amdgcn_cvt_pkrtz(a.z, a.w);
    auto h2 = __builtin_amdgcn_cvt_pkrtz(b.x, b.y);
    auto h3 = __builtin_amdgcn_cvt_pkrtz(b.z, b.w);
    hi[0] = static_cast<_Float16>(h0[0]); hi[1] = static_cast<_Float16>(h0[1]);
    hi[2] = static_cast<_Float16>(h1[0]); hi[3] = static_cast<_Float16>(h1[1]);
    hi[4] = static_cast<_Float16>(h2[0]); hi[5] = static_cast<_Float16>(h2[1]);
    hi[6] = static_cast<_Float16>(h3[0]); hi[7] = static_cast<_Float16>(h3[1]);
    float r0 = a.x - (float)h0[0], r1 = a.y - (float)h0[1];
    float r2 = a.z - (float)h1[0], r3 = a.w - (float)h1[1];
    float r4 = b.x - (float)h2[0], r5 = b.y - (float)h2[1];
    float r6 = b.z - (float)h3[0], r7 = b.w - (float)h3[1];
    auto l0 = __builtin_amdgcn_cvt_pkrtz(r0, r1);
    auto l1 = __builtin_amdgcn_cvt_pkrtz(r2, r3);
    auto l2 = __builtin_amdgcn_cvt_pkrtz(r4, r5);
    auto l3 = __builtin_amdgcn_cvt_pkrtz(r6, r7);
    lo[0] = static_cast<_Float16>(l0[0]); lo[1] = static_cast<_Float16>(l0[1]);
    lo[2] = static_cast<_Float16>(l1[0]); lo[3] = static_cast<_Float16>(l1[1]);
    lo[4] = static_cast<_Float16>(l2[0]); lo[5] = static_cast<_Float16>(l2[1]);
    lo[6] = static_cast<_Float16>(l3[0]); lo[7] = static_cast<_Float16>(l3[1]);
}

// ---- W prep: split fp32 W[d][e] into f16 hi/lo planes, laid out in exact
// B-fragment order: frag fi = ((ks*4 + tile)*2 + plane), 64 lanes x 16B each.
// Lane l of frag: expert = 16*tile + (l&15), k = ks*32 + (l>>4)*8 + j, j=0..7.
__global__ __launch_bounds__(256) void prep_w(const float* __restrict__ W,
                                              half8* __restrict__ ws) {
    const int gid  = blockIdx.x * 256 + threadIdx.x;   // 0..32767
    const int lane = gid & 63;
    const int fp   = gid >> 6;                         // 0..511 = ks*4 + tile
    const int t    = fp & 3;
    const int ks   = fp >> 2;
    const int e    = 16 * t + (lane & 15);
    const int k0   = ks * 32 + (lane >> 4) * 8;
    float4 a, b;
    a.x = W[(size_t)(k0 + 0) * NEXP + e];
    a.y = W[(size_t)(k0 + 1) * NEXP + e];
    a.z = W[(size_t)(k0 + 2) * NEXP + e];
    a.w = W[(size_t)(k0 + 3) * NEXP + e];
    b.x = W[(size_t)(k0 + 4) * NEXP + e];
    b.y = W[(size_t)(k0 + 5) * NEXP + e];
    b.z = W[(size_t)(k0 + 6) * NEXP + e];
    b.w = W[(size_t)(k0 + 7) * NEXP + e];
    half8 hi, lo;
    split8(a, b, hi, lo);
    ws[(size_t)(fp * 2 + 0) * 64 + lane] = hi;
    ws[(size_t)(fp * 2 + 1) * 64 + lane] = lo;
}

// ---- main: 16 tokens/block, expert-tile split across 4 waves (16 waves/CU) ----
__global__ __launch_bounds__(256, 4) void router_mfma(
    const float* __restrict__ x, const int4* __restrict__ wf,
    const float* __restrict__ b, float* __restrict__ out)
{
    __shared__ float ls[16][68];                       // [token][expert] exchange
    const int tid  = threadIdx.x;
    const int lane = tid & 63;
    const int wv   = tid >> 6;                         // = expert tile 0..3
    const int tok0 = blockIdx.x * 16;
    const int m    = lane & 15;                        // token row within tile
    const int q    = lane >> 4;                        // quad
    const float* __restrict__ xrow = x + (size_t)(tok0 + m) * D_MODEL + q * 8;

    f32x4 acc = {};                                    // 16 tok x 16 experts

    // depth-2 register prefetch: [buf][kstep][half]
    float4 xb[2][2][2];
    int4   wb[2][2][2];

    auto ldx = [&](int c, float4 (&dst)[2][2]) {
#pragma unroll
        for (int s = 0; s < 2; s++) {
            const float* p = xrow + (c * 2 + s) * 32;
            dst[s][0] = *(const float4*)p;
            dst[s][1] = *(const float4*)(p + 4);
        }
    };
    auto ldw = [&](int c, int4 (&dst)[2][2]) {
#pragma unroll
        for (int s = 0; s < 2; s++) {
            const int fi = ((c * 2 + s) * 4 + wv) * 2;
            dst[s][0] = wf[(size_t)fi * 64 + lane];
            dst[s][1] = wf[(size_t)(fi + 1) * 64 + lane];
        }
    };

    ldx(0, xb[0]); ldw(0, wb[0]);
    ldx(1, xb[1]); ldw(1, wb[1]);

#pragma unroll 2
    for (int c = 0; c < NCH; c++) {
        const int p = c & 1;
#pragma unroll
        for (int s = 0; s < 2; s++) {
            half8 ahi, alo;
            split8(xb[p][s][0], xb[p][s][1], ahi, alo);
            half8 bhi = __builtin_bit_cast(half8, wb[p][s][0]);
            half8 blo = __builtin_bit_cast(half8, wb[p][s][1]);
            acc = __builtin_amdgcn_mfma_f32_16x16x32_f16(ahi, bhi, acc, 0, 0, 0);
            acc = __builtin_amdgcn_mfma_f32_16x16x32_f16(ahi, blo, acc, 0, 0, 0);
            acc = __builtin_amdgcn_mfma_f32_16x16x32_f16(alo, bhi, acc, 0, 0, 0);
        }
        if (c + 2 < NCH) { ldx(c + 2, xb[p]); ldw(c + 2, wb[p]); }
    }

    // C/D layout (verified m89/m91): col = lane&15 (expert-in-tile), row = q*4 + reg (token)
#pragma unroll
    for (int r = 0; r < 4; r++)
        ls[q * 4 + r][wv * 16 + m] = acc[r];           // 2-way banks max = free
    __syncthreads();

    // epilogue: wave wv handles tokens 4*wv .. 4*wv+3; lane <-> expert
    const float bias = b[lane];
    float* __restrict__ probs_out = out;
    float* __restrict__ top_out   = out + (size_t)NTOK * NEXP;
    float* __restrict__ idx_out   = top_out + (size_t)NTOK * 2;

#pragma unroll 1
    for (int r2 = 0; r2 < 4; r2++) {
        const int trow  = wv * 4 + r2;
        const int token = tok0 + trow;
        float logit = ls[trow][lane] + bias;

        float mx = logit;
#pragma unroll
        for (int off = 32; off; off >>= 1) mx = fmaxf(mx, __shfl_xor(mx, off, 64));
        float ex = expf(logit - mx);
        float s = ex;
#pragma unroll
        for (int off = 32; off; off >>= 1) s += __shfl_xor(s, off, 64);
        float p = ex / s;
        probs_out[(size_t)token * NEXP + lane] = p;

        // top-1 (lowest index wins ties, matching lax.top_k)
        float v = p; int idx = lane;
#pragma unroll
        for (int off = 32; off; off >>= 1) {
            float ov = __shfl_xor(v, off, 64);
            int   oi = __shfl_xor(idx, off, 64);
            if (ov > v || (ov == v && oi < idx)) { v = ov; idx = oi; }
        }
        const float v1 = v; const int i1 = idx;
        // top-2
        v = (lane == i1) ? -1.0f : p; idx = lane;
#pragma unroll
        for (int off = 32; off; off >>= 1) {
            float ov = __shfl_xor(v, off, 64);
            int   oi = __shfl_xor(idx, off, 64);
            if (ov > v || (ov == v && oi < idx)) { v = ov; idx = oi; }
        }
        const float v2 = v; const int i2 = idx;

        if (lane == 0) {
            const float dnm = v1 + v2 + 1e-9f;
            top_out[(size_t)token * 2 + 0] = v1 / dnm;
            top_out[(size_t)token * 2 + 1] = v2 / dnm;
            idx_out[(size_t)token * 2 + 0] = (float)i1;
            idx_out[(size_t)token * 2 + 1] = (float)i2;
        }
    }
}

// ---- fallback (no workspace): round-2 validated structure ----
#define BK  128
#define BKP (BK + 4)
__device__ __forceinline__ float rl(float v, int l) {
    return __int_as_float(__builtin_amdgcn_readlane(__float_as_int(v), l));
}
__global__ __launch_bounds__(128) void router_fallback(
    const float* __restrict__ x, const float* __restrict__ W,
    const float* __restrict__ b, float* __restrict__ out)
{
    __shared__ float wt[NEXP * BKP];
    const int tid  = threadIdx.x;
    const int lane = tid & 63;
    const int wv   = __builtin_amdgcn_readfirstlane(tid >> 6);
    const int tok0 = blockIdx.x * 16 + wv * 8;
    const float* __restrict__ xw = x + (size_t)tok0 * D_MODEL;

    float2 xcur[8], xnxt[8];
#pragma unroll
    for (int t = 0; t < 8; t++)
        xcur[t] = *(const float2*)(xw + (size_t)t * D_MODEL + 2 * lane);
    float accm[8];
#pragma unroll
    for (int t = 0; t < 8; t++) accm[t] = 0.f;

    for (int c = 0; c < D_MODEL / BK; c++) {
        const int k0 = c * BK;
        if (c + 1 < D_MODEL / BK) {
#pragma unroll
            for (int t = 0; t < 8; t++)
                xnxt[t] = *(const float2*)(xw + (size_t)t * D_MODEL + (k0 + BK) + 2 * lane);
        }
#pragma unroll
        for (int i = 0; i < 16; i++) {
            int n  = i * 128 + tid;
            int dd = n >> 4;
            int e0 = (n & 15) * 4;
            float4 v = *(const float4*)(W + (size_t)(k0 + dd) * NEXP + e0);
            wt[(e0 + 0) * BKP + dd] = v.x;
            wt[(e0 + 1) * BKP + dd] = v.y;
            wt[(e0 + 2) * BKP + dd] = v.z;
            wt[(e0 + 3) * BKP + dd] = v.w;
        }
        __syncthreads();
        float acc[8];
#pragma unroll
        for (int t = 0; t < 8; t++) acc[t] = 0.f;
        const float* wl = &wt[lane * BKP];
#pragma unroll 4
        for (int kk = 0; kk < BK; kk += 4) {
            float4 w4 = *(const float4*)(wl + kk);
            const int l0 = kk >> 1;
#pragma unroll
            for (int t = 0; t < 8; t++) {
                float a = acc[t];
                a = fmaf(rl(xcur[t].x, l0    ), w4.x, a);
                a = fmaf(rl(xcur[t].y, l0    ), w4.y, a);
                a = fmaf(rl(xcur[t].x, l0 + 1), w4.z, a);
                a = fmaf(rl(xcur[t].y, l0 + 1), w4.w, a);
                acc[t] = a;
            }
        }
#pragma unroll
        for (int t = 0; t < 8; t++) accm[t] += acc[t];
        __syncthreads();
#pragma unroll
        for (int t = 0; t < 8; t++) xcur[t] = xnxt[t];
    }

    const float bias = b[lane];
    float* __restrict__ probs_out = out;
    float* __restrict__ top_out   = out + (size_t)NTOK * NEXP;
    float* __restrict__ idx_out   = top_out + (size_t)NTOK * 2;
#pragma unroll 1
    for (int t = 0; t < 8; t++) {
        const int token = tok0 + t;
        float logit = accm[t] + bias;
        float mx = logit;
#pragma unroll
        for (int off = 32; off; off >>= 1) mx = fmaxf(mx, __shfl_xor(mx, off, 64));
        float ex = expf(logit - mx);
        float s = ex;
#pragma unroll
        for (int off = 32; off; off >>= 1) s += __shfl_xor(s, off, 64);
        float p = ex / s;
        probs_out[(size_t)token * NEXP + lane] = p;
        float v = p; int idx = lane;
#pragma unroll
        for (int off = 32; off; off >>= 1) {
            float ov = __shfl_xor(v, off, 64);
            int   oi = __shfl_xor(idx, off, 64);
            if (ov > v || (ov == v && oi < idx)) { v = ov; idx = oi; }
        }
        const float v1 = v; const int i1 = idx;
        v = (lane == i1) ? -1.0f : p; idx = lane;
#pragma unroll
        for (int off = 32; off; off >>= 1) {
            float ov = __shfl_xor(v, off, 64);
            int   oi = __shfl_xor(idx, off, 64);
            if (ov > v || (ov == v && oi < idx)) { v = ov; idx = oi; }
        }
        const float v2 = v; const int i2 = idx;
        if (lane == 0) {
            const float dnm = v1 + v2 + 1e-9f;
            top_out[(size_t)token * 2 + 0] = v1 / dnm;
            top_out[(size_t)token * 2 + 1] = v2 / dnm;
            idx_out[(size_t)token * 2 + 0] = (float)i1;
            idx_out[(size_t)token * 2 + 1] = (float)i2;
        }
    }
}

extern "C" void kernel_launch(void* const* d_in, const int* in_sizes, int n_in,
                              void* d_out, int out_size, void* d_ws, size_t ws_size,
                              hipStream_t stream) {
    const float* x = (const float*)d_in[0];
    const float* W = (const float*)d_in[1];
    const float* b = (const float*)d_in[2];
    float* out = (float*)d_out;

    const size_t need = (size_t)NKS * 4 * 2 * 64 * 16;   // 1 MiB of f16 fragments
    if (ws_size >= need) {
        prep_w<<<128, 256, 0, stream>>>(W, (half8*)d_ws);
        router_mfma<<<NTOK / 16, 256, 0, stream>>>(x, (const int4*)d_ws, b, out);
    } else {
        router_fallback<<<NTOK / 16, 128, 0, stream>>>(x, W, b, out);
    }
}